// Round 5
// baseline (597.484 us; speedup 1.0000x reference)
//
#include <hip/hip_runtime.h>

// QuantLinear W4A32 — round 11: 8-phase 256x256 GEMM on 32x32x16_f16 MFMA.
//  * qgemm8: same verified 1-bar/phase schedule geometry; MFMA shape switched to
//    32x32x16 (11% faster pipe, half the instructions). Phases = (mb-pair x kb-pair):
//    8 MFMA/phase, 4 independent acc chains of length 2. Reads: 24 ds_read_b128 /
//    K-tile/wave (unchanged bytes). Hazard windows re-derived: A last-read now P4
//    -> A-prefetch at P6/P7; B at P4/P8 with vmcnt(4). Stage addrs = moving ptr +
//    compile-time offsets. A/B frag: row|col=lane&31, k=(lane>>5)*8+i.
//    C/D: col=lane&31, row=(reg&3)+8*(reg>>2)+4*(lane>>5) [HW-verified].
//  * prep_ab: unchanged (pre-swizzled slot ^= row&7 tiles).
// Fallbacks by ws_size: round-4 A-DMA path, then round-3 fully-fused path.

#define BK 32
#define LDK 40             // legacy padded row stride (fallback path)
#define TILE_BYTES 10240   // legacy A tile

typedef _Float16 v8h __attribute__((ext_vector_type(8)));
typedef _Float16 half2v __attribute__((ext_vector_type(2)));
typedef float v4f __attribute__((ext_vector_type(4)));
typedef float v16f __attribute__((ext_vector_type(16)));

__device__ __forceinline__ unsigned pkrtz_u32(float a, float b) {
  return __builtin_bit_cast(unsigned, __builtin_amdgcn_cvt_pkrtz(a, b));
}

__device__ __forceinline__ void load_lds_16B(const void* g, void* l) {
  __builtin_amdgcn_global_load_lds(
      (const __attribute__((address_space(1))) unsigned*)g,
      (__attribute__((address_space(3))) unsigned*)l, 16, 0, 0);
}

__device__ __forceinline__ void bar() { asm volatile("s_barrier" ::: "memory"); }

// ---------------- prep_ab: merged operand prep (unchanged) -------------------
__global__ __launch_bounds__(512)
void prep_ab(const float* __restrict__ x,
             const unsigned* __restrict__ qweight,
             const unsigned* __restrict__ qzeros,
             const float* __restrict__ scales,
             unsigned short* __restrict__ fa,
             unsigned short* __restrict__ fb, int M, int N, int K) {
  const int KT = K / 64;
  const int NA = (M / 256) * KT;
  int b = blockIdx.x;
  if (b < NA) {
    const int mt = b / KT, t = b - mt * KT;
    unsigned short* tile = fa + (size_t)(mt * KT + t) * 16384;
#pragma unroll
    for (int p = 0; p < 4; ++p) {
      const int c = threadIdx.x + p * 512;
      const int h = c >> 10, r = (c >> 3) & 127, s = c & 7;
      const float* src = x + (size_t)(mt * 256 + h * 128 + r) * K + t * 64 + s * 8;
      const float4 v0 = ((const float4*)src)[0];
      const float4 v1 = ((const float4*)src)[1];
      uint4 o;
      o.x = pkrtz_u32(v0.x, v0.y); o.y = pkrtz_u32(v0.z, v0.w);
      o.z = pkrtz_u32(v1.x, v1.y); o.w = pkrtz_u32(v1.z, v1.w);
      *(uint4*)(tile + h * 8192 + r * 64 + ((s ^ (r & 7)) << 3)) = o;
    }
  } else {
    b -= NA;
    const int nt = b / KT, t = b - nt * KT;
    const int g = t >> 1;  // GROUP=128 = 2 K-tiles
    unsigned short* tile = fb + (size_t)(nt * KT + t) * 16384;
#pragma unroll
    for (int p = 0; p < 4; ++p) {
      const int c = threadIdx.x + p * 512;
      const int h = c >> 10, r = (c >> 3) & 127, s = c & 7;
      const int n = nt * 256 + h * 128 + r;
      const unsigned zp = qzeros[(size_t)g * (N >> 3) + (n >> 3)];
      const float sc = scales[(size_t)g * N + n];
      const unsigned z = (zp >> ((n & 7) * 4)) & 15u;
      const unsigned hz_u = 0x64006400u | z | (z << 16);
      const half2v hz2 = __builtin_bit_cast(half2v, hz_u);
      const half2v hs2 = __builtin_bit_cast(half2v, pkrtz_u32(sc, sc));
      const unsigned qv = qweight[(size_t)(t * 8 + s) * N + n];
      uint4 o;
      unsigned* wp = (unsigned*)&o;
#pragma unroll
      for (int bb = 0; bb < 4; ++bb) {
        const unsigned byte = qv >> (8 * bb);
        const unsigned pq = 0x64006400u | (byte & 0xFu) | ((byte & 0xF0u) << 12);
        const half2v w2 = (__builtin_bit_cast(half2v, pq) - hz2) * hs2;
        wp[bb] = __builtin_bit_cast(unsigned, w2);
      }
      *(uint4*)(tile + h * 8192 + r * 64 + ((s ^ (r & 7)) << 3)) = o;
    }
  }
}

// ---------------- main: 8-phase 256x256, 32x32x16 MFMA, 1 bar/phase ----------

#define RDA(D, MB, KB2)                                                        \
  _Pragma("unroll") for (int kk = 0; kk < 2; ++kk)                             \
  _Pragma("unroll") for (int i = 0; i < 2; ++i)                                \
    aF[i][kk] = *(const v8h*)(vA[D][(KB2) * 2 + kk] + ((MB) + i) * 4096);

#define RDB(D, KB2, BF)                                                        \
  _Pragma("unroll") for (int kk = 0; kk < 2; ++kk)                             \
  _Pragma("unroll") for (int j = 0; j < 2; ++j)                                \
    BF[j][kk] = *(const v8h*)(vB[D][(KB2) * 2 + kk] + j * 4096);

#define MMA8(MB, BF)                                                           \
  __builtin_amdgcn_s_setprio(1);                                               \
  _Pragma("unroll") for (int kk = 0; kk < 2; ++kk)                             \
  _Pragma("unroll") for (int i = 0; i < 2; ++i)                                \
  _Pragma("unroll") for (int j = 0; j < 2; ++j)                                \
    acc[(MB) + i][j] = __builtin_amdgcn_mfma_f32_32x32x16_f16(                 \
        aF[i][kk], BF[j][kk], acc[(MB) + i][j], 0, 0, 0);                      \
  __builtin_amdgcn_s_setprio(0);

__global__ __launch_bounds__(512, 2)
void qgemm8(const unsigned short* __restrict__ fa,
            const unsigned short* __restrict__ fb,
            float* __restrict__ out, int M, int N, int K) {
  // [dbuf][half 128 rows][row][k] : 2*2*128*64*2B = 64KB each operand
  __shared__ __align__(16) short As[2][2][128][64];
  __shared__ __align__(16) short Bs[2][2][128][64];

  const int tid = threadIdx.x;
  const int lane = tid & 63;
  const int wid = tid >> 6;  // 8 waves: (wr 0..1) x (wc 0..3)
  const int wr = wid >> 2, wc = wid & 3;
  const int r31 = lane & 31, l7 = lane & 7, hk = lane >> 5;

  const int nmt = M / 256;            // 16
  const int nwg = nmt * (N / 256);    // 688 (divisible by 8)
  int bid = blockIdx.x;
  {
    const int xcd = bid & 7, idx = bid >> 3;
    const int q = nwg >> 3, r = nwg & 7;
    bid = (xcd < r ? xcd * (q + 1) : r * (q + 1) + (xcd - r) * q) + idx;
  }
  const int mt = bid % nmt;  // m fastest -> W panel L2-resident per XCD
  const int nt = bid / nmt;

  const int NT = K / 64;    // 64 K-tiles
  const int NI = NT / 2;    // 32 iterations (2 K-tiles each)

  const char* sA = (const char*)fa + (size_t)mt * NT * 32768 + wid * 1024 + lane * 16;
  const char* sB = (const char*)fb + (size_t)nt * NT * 32768 + wid * 1024 + lane * 16;
  char* ldsA = (char*)&As[0][0][0][0];
  char* ldsB = (char*)&Bs[0][0][0][0];
  char* dA = ldsA + wid * 1024;  // HW appends lane*16
  char* dB = ldsB + wid * 1024;

  // ds_read bases per (dbuf, kb): row=lane&31, phys slot=((lane>>5)+2kb)^(lane&7)
  const char* vA[2][4];
  const char* vB[2][4];
#pragma unroll
  for (int d = 0; d < 2; ++d)
#pragma unroll
    for (int kb = 0; kb < 4; ++kb) {
      const int T = r31 * 128 + (((hk + 2 * kb) ^ l7) << 4);
      vA[d][kb] = ldsA + d * 32768 + wr * 16384 + T;
      vB[d][kb] = ldsB + d * 32768 + (wc >> 1) * 16384 + (wc & 1) * 8192 + T;
    }

  auto stA = [&](int so, int dof) {
    load_lds_16B(sA + so, dA + dof);
    load_lds_16B(sA + so + 8192, dA + dof + 8192);
  };
  auto stB = [&](int so, int dof) {
    load_lds_16B(sB + so, dB + dof);
    load_lds_16B(sB + so + 8192, dB + dof + 8192);
  };

  v16f acc[4][2] = {};           // [mb 32-row block][nb 32-col block]
  v8h aF[2][2], bE[2][2], bO[2][2];  // [i|j][kk]

  // ---- prologue: t0 {B,A}, t1 {B}; wait t0 landed (t1-B 4 in flight) ----
  stB(0, 0); stB(16384, 16384);
  stA(0, 0); stA(16384, 16384);
  stB(32768, 32768); stB(49152, 49152);
  asm volatile("s_waitcnt vmcnt(4)");
  bar();

  for (int it = 0; it < NI; ++it) {
    const bool pf = (it < NI - 1);

    // ======== K-tile t0 (dbuf 0) ========
    // P1: A(mb01,kb01)+B(kb01)
    RDA(0, 0, 0); RDB(0, 0, bE);
    bar();
    MMA8(0, bE);
    // P2: A(mb01,kb23)+B(kb23) ; stage A(t1,h0) [dbuf1-A last read prev P8 -> +2 OK]
    RDA(0, 0, 1); RDB(0, 1, bO);
    stA(32768, 32768);
    bar();
    MMA8(0, bO);
    // P3: A(mb23,kb01) ; stage A(t1,h1)
    RDA(0, 2, 0);
    stA(49152, 49152);
    bar();
    MMA8(2, bE);
    // P4: A(mb23,kb23) ; stage B(t0+2) [dbuf0-B last read P2 -> P4 OK];
    //     wait: drain t1 A+B (8), leave B(t0+2) (4)
    RDA(0, 2, 1);
    if (pf) { stB(65536, 0); stB(81920, 16384);
              asm volatile("s_waitcnt vmcnt(4)"); }
    else    { asm volatile("s_waitcnt vmcnt(0)"); }
    bar();
    MMA8(2, bO);

    // ======== K-tile t1 (dbuf 1) ========
    // P5: A(mb01,kb01)+B(kb01)
    RDA(1, 0, 0); RDB(1, 0, bE);
    bar();
    MMA8(0, bE);
    // P6: A(mb01,kb23)+B(kb23) ; stage A(t0+2,h0) [dbuf0-A last read P4 -> P6 OK]
    RDA(1, 0, 1); RDB(1, 1, bO);
    if (pf) stA(65536, 0);
    bar();
    MMA8(0, bO);
    // P7: A(mb23,kb01) ; stage A(t0+2,h1)
    RDA(1, 2, 0);
    if (pf) stA(81920, 16384);
    bar();
    MMA8(2, bE);
    // P8: A(mb23,kb23) ; stage B(t1+2) [dbuf1-B last read P6 -> P8 OK];
    //     wait: drain t0+2 A+B (8), leave B(t1+2) (4)
    RDA(1, 2, 1);
    if (pf) { stB(98304, 32768); stB(114688, 49152);
              asm volatile("s_waitcnt vmcnt(4)"); }
    else    { asm volatile("s_waitcnt vmcnt(0)"); }
    bar();
    MMA8(2, bO);

    sA += 65536; sB += 65536;
  }

  // ---- epilogue: 32x32 C/D: col=lane&31, row=(reg&3)+8*(reg>>2)+4*(lane>>5) ----
  const int m0 = mt * 256 + wr * 128;
  const int n0 = nt * 256 + wc * 64;
  const int orow = 4 * hk;
#pragma unroll
  for (int mb = 0; mb < 4; ++mb)
#pragma unroll
    for (int nb = 0; nb < 2; ++nb)
#pragma unroll
      for (int reg = 0; reg < 16; ++reg) {
        const int row = m0 + mb * 32 + orow + (reg & 3) + 8 * (reg >> 2);
        const int col = n0 + nb * 32 + r31;
        out[(size_t)row * N + col] = acc[mb][nb][reg];
      }
}

// ---------------- legacy prep_x (fallback path) ------------------------------
__global__ __launch_bounds__(320)
void prep_x(const float* __restrict__ x, unsigned short* __restrict__ xt, int K) {
  const int kt = blockIdx.x, mt = blockIdx.y;
  unsigned short* tile = xt + (size_t)(mt * (K / 32) + kt) * (TILE_BYTES / 2);
#pragma unroll
  for (int p = 0; p < 2; ++p) {
    const int c = threadIdx.x + p * 320;
    const int r = c / 5, j = c - r * 5;
    uint4 o = {0u, 0u, 0u, 0u};
    if (j < 4) {
      const float* src = x + (size_t)(mt * 128 + r) * K + kt * 32 + j * 8;
      const float4 v0 = ((const float4*)src)[0];
      const float4 v1 = ((const float4*)src)[1];
      o.x = pkrtz_u32(v0.x, v0.y); o.y = pkrtz_u32(v0.z, v0.w);
      o.z = pkrtz_u32(v1.x, v1.y); o.w = pkrtz_u32(v1.z, v1.w);
    }
    *(uint4*)((char*)tile + (size_t)c * 16) = o;
  }
}

// ---------------- fallback 1: round-4 (A DMA, B fused dequant) ----------------
__global__ __launch_bounds__(512, 4)
void qgemm_dma(const unsigned short* __restrict__ xt,
               const unsigned* __restrict__ qweight,
               const unsigned* __restrict__ qzeros,
               const float* __restrict__ scales,
               float* __restrict__ out, int M, int N, int K) {
  __shared__ __align__(16) short As[128][LDK];
  __shared__ __align__(16) short Bs[256][LDK];

  const int tid = threadIdx.x;
  const int lane = tid & 63;
  const int wid = tid >> 6;
  const int n0 = blockIdx.x * 256;
  const int m0 = blockIdx.y * 128;
  const int mt = blockIdx.y;
  const int wm = (wid >> 2) * 64;
  const int wn = (wid & 3) * 64;
  const int lr = lane & 15;
  const int lk = (lane >> 4) * 8;

  const int b_n = tid & 255;
  const int b_kr0 = tid >> 8;
  const int gn = n0 + b_n;
  const unsigned* qwb = qweight + (size_t)b_kr0 * N + gn;

  const char* xt_b = (const char*)xt;
  const int NT = K / BK;

  v4f acc[4][4] = {};

  unsigned b0c, b1c, zpc;
  float scc;
  auto load_b = [&](int t, unsigned& b0, unsigned& b1, unsigned& zp, float& sc) {
    const int kk = t * BK;
    const size_t qoff = (size_t)(kk >> 3) * N;
    b0 = qwb[qoff];
    b1 = qwb[qoff + 2 * (size_t)N];
    const int g = kk >> 7;
    zp = qzeros[(size_t)g * (N >> 3) + (gn >> 3)];
    sc = scales[(size_t)g * N + gn];
  };
  load_b(0, b0c, b1c, zpc, scc);

#pragma unroll 2
  for (int t = 0; t < NT; ++t) {
    {
      const char* g = xt_b + (size_t)(mt * NT + t) * TILE_BYTES +
                      (size_t)wid * 1024 + (size_t)lane * 16;
      char* l = ((char*)&As[0][0]) + wid * 1024;
      load_lds_16B(g, l);
      if (wid < 2) load_lds_16B(g + 8 * 1024, l + 8 * 1024);
    }
    {
      const unsigned z = (zpc >> ((gn & 7) * 4)) & 15u;
      const unsigned hz_u = 0x64006400u | z | (z << 16);
      const half2v hz2 = __builtin_bit_cast(half2v, hz_u);
      const half2v hs2 = __builtin_bit_cast(half2v, pkrtz_u32(scc, scc));
      const unsigned qvs[2] = {b0c, b1c};
#pragma unroll
      for (int q = 0; q < 2; ++q) {
        const int kr = b_kr0 + q * 2;
        const unsigned qv = qvs[q];
        uint4 wv;
        unsigned* wp = (unsigned*)&wv;
#pragma unroll
        for (int j = 0; j < 4; ++j) {
          const unsigned byte = qv >> (8 * j);
          const unsigned pq = 0x64006400u | (byte & 0xFu) | ((byte & 0xF0u) << 12);
          const half2v w2 = (__builtin_bit_cast(half2v, pq) - hz2) * hs2;
          wp[j] = __builtin_bit_cast(unsigned, w2);
        }
        *(uint4*)(&Bs[b_n][kr * 8]) = wv;
      }
    }

    __syncthreads();

    unsigned b0n, b1n, zpn;
    float scn;
    const int tn = (t + 1 < NT) ? (t + 1) : t;
    load_b(tn, b0n, b1n, zpn, scn);

    v8h af[4], bfr[4];
#pragma unroll
    for (int i = 0; i < 4; ++i) {
      af[i] = *(const v8h*)(&As[wm + i * 16 + lr][lk]);
      bfr[i] = *(const v8h*)(&Bs[wn + i * 16 + lr][lk]);
    }
#pragma unroll
    for (int mi = 0; mi < 4; ++mi) {
#pragma unroll
      for (int ni = 0; ni < 4; ++ni) {
        acc[mi][ni] = __builtin_amdgcn_mfma_f32_16x16x32_f16(
            af[mi], bfr[ni], acc[mi][ni], 0, 0, 0);
      }
    }

    __syncthreads();

    b0c = b0n; b1c = b1n; zpc = zpn; scc = scn;
  }

#pragma unroll
  for (int mi = 0; mi < 4; ++mi) {
#pragma unroll
    for (int ni = 0; ni < 4; ++ni) {
#pragma unroll
      for (int r = 0; r < 4; ++r) {
        const int row = m0 + wm + mi * 16 + (lane >> 4) * 4 + r;
        const int col = n0 + wn + ni * 16 + lr;
        out[(size_t)row * N + col] = acc[mi][ni][r];
      }
    }
  }
}

// ---------------- fallback 2: round-3 fully fused (128x128) ----------------
__global__ __launch_bounds__(256, 2)
void qgemm_fused(const float* __restrict__ x,
                 const unsigned* __restrict__ qweight,
                 const unsigned* __restrict__ qzeros,
                 const float* __restrict__ scales,
                 float* __restrict__ out, int M, int N, int K) {
  __shared__ short As[128][LDK];
  __shared__ short Bs[128][LDK];

  const int tid = threadIdx.x;
  const int lane = tid & 63;
  const int wid = tid >> 6;
  const int n0 = blockIdx.x * 128;
  const int m0 = blockIdx.y * 128;
  const int wm = (wid >> 1) * 64;
  const int wn = (wid & 1) * 64;
  const int lr = lane & 15;
  const int lk = (lane >> 4) * 8;

  const int a_row = tid >> 3;
  const int a_col = (tid & 7) * 4;
  const int b_n = tid & 127;
  const int b_kr0 = tid >> 7;
  const int gn = n0 + b_n;

  const float* xb = x + (size_t)(m0 + a_row) * K + a_col;
  const unsigned* qwb = qweight + (size_t)b_kr0 * N + gn;

  v4f acc[4][4] = {};
  const int NT = K / BK;

  float4 axc[4];
  unsigned b0c, b1c, zpc;
  float scc;

  auto load_step = [&](int t, float4 ax[4], unsigned& b0, unsigned& b1,
                       unsigned& zp, float& sc) {
    const int kk = t * BK;
#pragma unroll
    for (int p = 0; p < 4; ++p)
      ax[p] = *(const float4*)(xb + (size_t)(p * 32) * K + kk);
    const size_t qoff = (size_t)(kk >> 3) * N;
    b0 = qwb[qoff];
    b1 = qwb[qoff + 2 * (size_t)N];
    const int g = kk >> 7;
    zp = qzeros[(size_t)g * (N >> 3) + (gn >> 3)];
    sc = scales[(size_t)g * N + gn];
  };

  load_step(0, axc, b0c, b1c, zpc, scc);

#pragma unroll 2
  for (int t = 0; t < NT; ++t) {
    const unsigned z = (zpc >> ((gn & 7) * 4)) & 15u;
    const unsigned hz_u = 0x64006400u | z | (z << 16);
    const half2v hz2 = __builtin_bit_cast(half2v, hz_u);
    const half2v hs2 = __builtin_bit_cast(half2v, pkrtz_u32(scc, scc));

#pragma unroll
    for (int p = 0; p < 4; ++p) {
      const int row = p * 32 + a_row;
      uint2 pv;
      pv.x = pkrtz_u32(axc[p].x, axc[p].y);
      pv.y = pkrtz_u32(axc[p].z, axc[p].w);
      *(uint2*)(&As[row][a_col]) = pv;
    }
    {
      const unsigned qvs[2] = {b0c, b1c};
#pragma unroll
      for (int q = 0; q < 2; ++q) {
        const int kr = b_kr0 + q * 2;
        const unsigned qv = qvs[q];
        uint4 wv;
        unsigned* wp = (unsigned*)&wv;
#pragma unroll
        for (int j = 0; j < 4; ++j) {
          const unsigned byte = qv >> (8 * j);
          const unsigned pq = 0x64006400u | (byte & 0xFu) | ((byte & 0xF0u) << 12);
          const half2v w2 = (__builtin_bit_cast(half2v, pq) - hz2) * hs2;
          wp[j] = __builtin_bit_cast(unsigned, w2);
        }
        *(uint4*)(&Bs[b_n][kr * 8]) = wv;
      }
    }

    __syncthreads();

    float4 axn[4];
    unsigned b0n, b1n, zpn;
    float scn;
    const int tn = (t + 1 < NT) ? (t + 1) : t;
    load_step(tn, axn, b0n, b1n, zpn, scn);

    v8h af[4], bfr[4];
#pragma unroll
    for (int i = 0; i < 4; ++i) {
      af[i] = *(const v8h*)(&As[wm + i * 16 + lr][lk]);
      bfr[i] = *(const v8h*)(&Bs[wn + i * 16 + lr][lk]);
    }
#pragma unroll
    for (int mi = 0; mi < 4; ++mi) {
#pragma unroll
      for (int ni = 0; ni < 4; ++ni) {
        acc[mi][ni] = __builtin_amdgcn_mfma_f32_16x16x32_f16(
            af[mi], bfr[ni], acc[mi][ni], 0, 0, 0);
      }
    }

    __syncthreads();

#pragma unroll
    for (int p = 0; p < 4; ++p) axc[p] = axn[p];
    b0c = b0n; b1c = b1n; zpc = zpn; scc = scn;
  }

#pragma unroll
  for (int mi = 0; mi < 4; ++mi) {
#pragma unroll
    for (int ni = 0; ni < 4; ++ni) {
#pragma unroll
      for (int r = 0; r < 4; ++r) {
        const int row = m0 + wm + mi * 16 + (lane >> 4) * 4 + r;
        const int col = n0 + wn + ni * 16 + lr;
        out[(size_t)row * N + col] = acc[mi][ni][r];
      }
    }
  }
}

extern "C" void kernel_launch(void* const* d_in, const int* in_sizes, int n_in,
                              void* d_out, int out_size, void* d_ws, size_t ws_size,
                              hipStream_t stream) {
  const float* x = (const float*)d_in[0];
  const unsigned* qweight = (const unsigned*)d_in[1];
  const unsigned* qzeros = (const unsigned*)d_in[2];
  const float* scales = (const float*)d_in[3];
  float* out = (float*)d_out;

  const int K = 4096;
  const int N = 11008;
  const int M = in_sizes[0] / K;  // 4096

  const size_t A8 = (size_t)(M / 256) * (K / 64) * 32768;  // 33.6 MB
  const size_t B8 = (size_t)(N / 256) * (K / 64) * 32768;  // 90.2 MB
  const size_t A_BYTES = (size_t)(M / 128) * (K / 32) * TILE_BYTES;  // legacy

  if ((M % 256 == 0) && ws_size >= A8 + B8) {
    unsigned short* fa = (unsigned short*)d_ws;
    unsigned short* fb = (unsigned short*)((char*)d_ws + A8);
    const int nblk = (M / 256) * (K / 64) + (N / 256) * (K / 64);
    prep_ab<<<dim3(nblk), 512, 0, stream>>>(x, qweight, qzeros, scales, fa, fb, M, N, K);
    qgemm8<<<dim3((M / 256) * (N / 256)), 512, 0, stream>>>(fa, fb, out, M, N, K);
  } else if (ws_size >= A_BYTES) {
    unsigned short* xt = (unsigned short*)d_ws;
    prep_x<<<dim3(K / 32, M / 128), 320, 0, stream>>>(x, xt, K);
    qgemm_dma<<<dim3(N / 256, M / 128), 512, 0, stream>>>(xt, qweight, qzeros, scales,
                                                          out, M, N, K);
  } else {
    qgemm_fused<<<dim3(N / 128, M / 128), 256, 0, stream>>>(x, qweight, qzeros, scales,
                                                            out, M, N, K);
  }
}

// Round 6
// 560.268 us; speedup vs baseline: 1.0664x; 1.0664x over previous
//
#include <hip/hip_runtime.h>

// QuantLinear W4A32 — round 12: round-10 structure (reverted from 32x32 regression)
// + in-register fragment pipelining (issue-early ds_reads).
//  * qgemm8: 16x16x32 MFMA, 256x256 tile, 1 bar/phase, verified round-10 schedule.
//    NEW: per K-tile, P1 issues ALL aLo+bL+bH reads (16), P2 issues aHi into a
//    SEPARATE reg set aG; P3/P4 compute from registers (no reads). lgkmcnt waits
//    become FIFO-prefix waits (4/8/0) instead of full-latency stalls.
//    Hazard margins unchanged: every region's reads complete >=2 bars before its
//    overwriting stage (bH read P1 / staged P4; aG read P2 / staged next P1-P2).
//  * prep_ab: merged A/B prep, pre-swizzled (slot ^= row&7), unchanged.
// Fallbacks by ws_size: round-4 A-DMA path, then round-3 fully-fused path.

#define BK 32
#define LDK 40             // legacy padded row stride (fallback path)
#define TILE_BYTES 10240   // legacy A tile

typedef _Float16 v8h __attribute__((ext_vector_type(8)));
typedef _Float16 half2v __attribute__((ext_vector_type(2)));
typedef float v4f __attribute__((ext_vector_type(4)));

__device__ __forceinline__ unsigned pkrtz_u32(float a, float b) {
  return __builtin_bit_cast(unsigned, __builtin_amdgcn_cvt_pkrtz(a, b));
}

__device__ __forceinline__ void load_lds_16B(const void* g, void* l) {
  __builtin_amdgcn_global_load_lds(
      (const __attribute__((address_space(1))) unsigned*)g,
      (__attribute__((address_space(3))) unsigned*)l, 16, 0, 0);
}

__device__ __forceinline__ void bar() { asm volatile("s_barrier" ::: "memory"); }

// ---------------- prep_ab: merged operand prep (unchanged) -------------------
__global__ __launch_bounds__(512)
void prep_ab(const float* __restrict__ x,
             const unsigned* __restrict__ qweight,
             const unsigned* __restrict__ qzeros,
             const float* __restrict__ scales,
             unsigned short* __restrict__ fa,
             unsigned short* __restrict__ fb, int M, int N, int K) {
  const int KT = K / 64;
  const int NA = (M / 256) * KT;
  int b = blockIdx.x;
  if (b < NA) {
    const int mt = b / KT, t = b - mt * KT;
    unsigned short* tile = fa + (size_t)(mt * KT + t) * 16384;
#pragma unroll
    for (int p = 0; p < 4; ++p) {
      const int c = threadIdx.x + p * 512;
      const int h = c >> 10, r = (c >> 3) & 127, s = c & 7;
      const float* src = x + (size_t)(mt * 256 + h * 128 + r) * K + t * 64 + s * 8;
      const float4 v0 = ((const float4*)src)[0];
      const float4 v1 = ((const float4*)src)[1];
      uint4 o;
      o.x = pkrtz_u32(v0.x, v0.y); o.y = pkrtz_u32(v0.z, v0.w);
      o.z = pkrtz_u32(v1.x, v1.y); o.w = pkrtz_u32(v1.z, v1.w);
      *(uint4*)(tile + h * 8192 + r * 64 + ((s ^ (r & 7)) << 3)) = o;
    }
  } else {
    b -= NA;
    const int nt = b / KT, t = b - nt * KT;
    const int g = t >> 1;  // GROUP=128 = 2 K-tiles
    unsigned short* tile = fb + (size_t)(nt * KT + t) * 16384;
#pragma unroll
    for (int p = 0; p < 4; ++p) {
      const int c = threadIdx.x + p * 512;
      const int h = c >> 10, r = (c >> 3) & 127, s = c & 7;
      const int n = nt * 256 + h * 128 + r;
      const unsigned zp = qzeros[(size_t)g * (N >> 3) + (n >> 3)];
      const float sc = scales[(size_t)g * N + n];
      const unsigned z = (zp >> ((n & 7) * 4)) & 15u;
      const unsigned hz_u = 0x64006400u | z | (z << 16);
      const half2v hz2 = __builtin_bit_cast(half2v, hz_u);
      const half2v hs2 = __builtin_bit_cast(half2v, pkrtz_u32(sc, sc));
      const unsigned qv = qweight[(size_t)(t * 8 + s) * N + n];
      uint4 o;
      unsigned* wp = (unsigned*)&o;
#pragma unroll
      for (int bb = 0; bb < 4; ++bb) {
        const unsigned byte = qv >> (8 * bb);
        const unsigned pq = 0x64006400u | (byte & 0xFu) | ((byte & 0xF0u) << 12);
        const half2v w2 = (__builtin_bit_cast(half2v, pq) - hz2) * hs2;
        wp[bb] = __builtin_bit_cast(unsigned, w2);
      }
      *(uint4*)(tile + h * 8192 + r * 64 + ((s ^ (r & 7)) << 3)) = o;
    }
  }
}

// ---------------- main: 8-phase 256x256, 1 bar/phase, reg-pipelined reads ----

#define READA4(SET, D, MB)                                                     \
  _Pragma("unroll") for (int i = 0; i < 4; ++i) {                              \
    SET[i][0] = *(const v8h*)(rdA##D##0 + (MB + i) * 2048);                    \
    SET[i][1] = *(const v8h*)(rdA##D##1 + (MB + i) * 2048);                    \
  }

#define READB2(D, BF, NB)                                                      \
  _Pragma("unroll") for (int j = 0; j < 2; ++j) {                              \
    BF[j][0] = *(const v8h*)(rdB##D##0 + (NB + j) * 2048);                     \
    BF[j][1] = *(const v8h*)(rdB##D##1 + (NB + j) * 2048);                     \
  }

// k-slot OUTER: 8 independent MFMAs between accumulator reuses.
#define MMAQ(ASET, MB, NB, BF)                                                 \
  __builtin_amdgcn_s_setprio(1);                                               \
  _Pragma("unroll") for (int s = 0; s < 2; ++s)                                \
  _Pragma("unroll") for (int i = 0; i < 4; ++i)                                \
  _Pragma("unroll") for (int j = 0; j < 2; ++j) {                              \
    acc[MB + i][NB + j] = __builtin_amdgcn_mfma_f32_16x16x32_f16(              \
        ASET[i][s], BF[j][s], acc[MB + i][NB + j], 0, 0, 0);                   \
  }                                                                            \
  __builtin_amdgcn_s_setprio(0);

__global__ __launch_bounds__(512, 2)
void qgemm8(const unsigned short* __restrict__ fa,
            const unsigned short* __restrict__ fb,
            float* __restrict__ out, int M, int N, int K) {
  // [dbuf][half 128 rows][row][k] : 2*2*128*64*2B = 64KB each operand
  __shared__ __align__(16) short As[2][2][128][64];
  __shared__ __align__(16) short Bs[2][2][128][64];

  const int tid = threadIdx.x;
  const int lane = tid & 63;
  const int wid = tid >> 6;  // 8 waves: (wr 0..1) x (wc 0..3)
  const int wr = wid >> 2, wc = wid & 3;
  const int lr16 = lane & 15, hi4 = lane >> 4, l7 = lane & 7;
  const int koff0 = ((hi4 ^ l7) << 4);        // ks=0 slot
  const int koff1 = (((4 + hi4) ^ l7) << 4);  // ks=1 slot

  const int nmt = M / 256;            // 16
  const int nwg = nmt * (N / 256);    // 688 (divisible by 8)
  int bid = blockIdx.x;
  {
    const int xcd = bid & 7, idx = bid >> 3;
    const int q = nwg >> 3, r = nwg & 7;
    bid = (xcd < r ? xcd * (q + 1) : r * (q + 1) + (xcd - r) * q) + idx;
  }
  const int mt = bid % nmt;  // m fastest -> W panel L2-resident per XCD
  const int nt = bid / nmt;

  const int NT = K / 64;    // 64 K-tiles
  const int NI = NT / 2;    // 32 iterations (2 K-tiles each)

  const char* srcA = (const char*)fa + (size_t)mt * NT * 32768 + wid * 1024 + lane * 16;
  const char* srcB = (const char*)fb + (size_t)nt * NT * 32768 + wid * 1024 + lane * 16;
  char* ldsA = (char*)&As[0][0][0][0];
  char* ldsB = (char*)&Bs[0][0][0][0];
  char* dstA = ldsA + wid * 1024;  // HW appends lane*16
  char* dstB = ldsB + wid * 1024;

  auto stageA = [&](int T, int h) {
    const char* s = srcA + (size_t)T * 32768 + h * 16384;
    char* d = dstA + (T & 1) * 32768 + h * 16384;
    load_lds_16B(s, d);
    load_lds_16B(s + 8192, d + 8192);
  };
  auto stageB = [&](int T, int h) {
    const char* s = srcB + (size_t)T * 32768 + h * 16384;
    char* d = dstB + (T & 1) * 32768 + h * 16384;
    load_lds_16B(s, d);
    load_lds_16B(s + 8192, d + 8192);
  };

  // Precomputed ds_read bases (verified round-10).
  const char* rdA00 = ldsA + wr * 16384 + lr16 * 128 + koff0;
  const char* rdA01 = ldsA + wr * 16384 + lr16 * 128 + koff1;
  const char* rdA10 = rdA00 + 32768;
  const char* rdA11 = rdA01 + 32768;
  const char* rdB00 = ldsB + (wc >> 1) * 16384 + (wc & 1) * 8192 + lr16 * 128 + koff0;
  const char* rdB01 = ldsB + (wc >> 1) * 16384 + (wc & 1) * 8192 + lr16 * 128 + koff1;
  const char* rdB10 = rdB00 + 32768;
  const char* rdB11 = rdB01 + 32768;

  v4f acc[8][4] = {};
  v8h aF[4][2], aG[4][2], bL[2][2], bH[2][2];

  // ---- prologue: t0 {B,A}, t1 {B}; wait t0 landed (t1-B 4 in flight) ----
  stageB(0, 0); stageB(0, 1); stageA(0, 0); stageA(0, 1);
  stageB(1, 0); stageB(1, 1);
  asm volatile("s_waitcnt vmcnt(4)");
  bar();

  for (int it = 0; it < NI; ++it) {
    const int t0 = 2 * it, t1 = 2 * it + 1;
    const bool pf = (it < NI - 1);

    // ======== K-tile t0 (dbuf 0) ========
    // P1: issue ALL t0 frag reads: aF (8), bL (4), bH (4); stage A(t1,h0).
    //     Q1 needs aF+bL = FIFO prefix 12 -> lgkmcnt(4) keeps bH in flight.
    READA4(aF, 0, 0);
    READB2(0, bL, 0);
    READB2(0, bH, 2);
    stageA(t1, 0);
    bar();
    MMAQ(aF, 0, 0, bL);
    // P2: issue aHi into aG (8); stage A(t1,h1). Q2 needs bH -> lgkmcnt(8).
    READA4(aG, 0, 4);
    stageA(t1, 1);
    bar();
    MMAQ(aF, 0, 2, bH);
    // P3: no reads (aG drains: lgkmcnt(0)).
    bar();
    MMAQ(aG, 4, 0, bL);
    // P4: stage B(t0+2) [dbuf0-B last LDS-read P1 -> P4 OK]; counted wait:
    //     drain t1 A+B (8 loads), leave B(t0+2) (4) in flight. Q4: regs only.
    if (pf) { stageB(t0 + 2, 0); stageB(t0 + 2, 1);
              asm volatile("s_waitcnt vmcnt(4)"); }
    else    { asm volatile("s_waitcnt vmcnt(0)"); }
    bar();
    MMAQ(aG, 4, 2, bH);

    // ======== K-tile t1 (dbuf 1) ========
    // P5: issue ALL t1 frag reads; stage A(t0+2,h0) [dbuf0-A last read P2 -> OK]
    READA4(aF, 1, 0);
    READB2(1, bL, 0);
    READB2(1, bH, 2);
    if (pf) stageA(t0 + 2, 0);
    bar();
    MMAQ(aF, 0, 0, bL);
    // P6: aG reads; stage A(t0+2,h1)
    READA4(aG, 1, 4);
    if (pf) stageA(t0 + 2, 1);
    bar();
    MMAQ(aF, 0, 2, bH);
    // P7: no reads
    bar();
    MMAQ(aG, 4, 0, bL);
    // P8: stage B(t1+2) [dbuf1-B last read P5 -> P8 OK]; counted wait as P4.
    if (pf) { stageB(t1 + 2, 0); stageB(t1 + 2, 1);
              asm volatile("s_waitcnt vmcnt(4)"); }
    else    { asm volatile("s_waitcnt vmcnt(0)"); }
    bar();
    MMAQ(aG, 4, 2, bH);
  }

  // ---- epilogue: C/D layout col=lane&15, row=(lane>>4)*4+reg ----
  const int m0 = mt * 256 + wr * 128;
  const int n0 = nt * 256 + wc * 64;
  float* obase = out + (size_t)(m0 + hi4 * 4) * N + n0 + lr16;
#pragma unroll
  for (int mi = 0; mi < 8; ++mi) {
#pragma unroll
    for (int ni = 0; ni < 4; ++ni) {
#pragma unroll
      for (int r = 0; r < 4; ++r) {
        obase[(size_t)(mi * 16 + r) * N + ni * 16] = acc[mi][ni][r];
      }
    }
  }
}

// ---------------- legacy prep_x (fallback path) ------------------------------
__global__ __launch_bounds__(320)
void prep_x(const float* __restrict__ x, unsigned short* __restrict__ xt, int K) {
  const int kt = blockIdx.x, mt = blockIdx.y;
  unsigned short* tile = xt + (size_t)(mt * (K / 32) + kt) * (TILE_BYTES / 2);
#pragma unroll
  for (int p = 0; p < 2; ++p) {
    const int c = threadIdx.x + p * 320;
    const int r = c / 5, j = c - r * 5;
    uint4 o = {0u, 0u, 0u, 0u};
    if (j < 4) {
      const float* src = x + (size_t)(mt * 128 + r) * K + kt * 32 + j * 8;
      const float4 v0 = ((const float4*)src)[0];
      const float4 v1 = ((const float4*)src)[1];
      o.x = pkrtz_u32(v0.x, v0.y); o.y = pkrtz_u32(v0.z, v0.w);
      o.z = pkrtz_u32(v1.x, v1.y); o.w = pkrtz_u32(v1.z, v1.w);
    }
    *(uint4*)((char*)tile + (size_t)c * 16) = o;
  }
}

// ---------------- fallback 1: round-4 (A DMA, B fused dequant) ----------------
__global__ __launch_bounds__(512, 4)
void qgemm_dma(const unsigned short* __restrict__ xt,
               const unsigned* __restrict__ qweight,
               const unsigned* __restrict__ qzeros,
               const float* __restrict__ scales,
               float* __restrict__ out, int M, int N, int K) {
  __shared__ __align__(16) short As[128][LDK];
  __shared__ __align__(16) short Bs[256][LDK];

  const int tid = threadIdx.x;
  const int lane = tid & 63;
  const int wid = tid >> 6;
  const int n0 = blockIdx.x * 256;
  const int m0 = blockIdx.y * 128;
  const int mt = blockIdx.y;
  const int wm = (wid >> 2) * 64;
  const int wn = (wid & 3) * 64;
  const int lr = lane & 15;
  const int lk = (lane >> 4) * 8;

  const int b_n = tid & 255;
  const int b_kr0 = tid >> 8;
  const int gn = n0 + b_n;
  const unsigned* qwb = qweight + (size_t)b_kr0 * N + gn;

  const char* xt_b = (const char*)xt;
  const int NT = K / BK;

  v4f acc[4][4] = {};

  unsigned b0c, b1c, zpc;
  float scc;
  auto load_b = [&](int t, unsigned& b0, unsigned& b1, unsigned& zp, float& sc) {
    const int kk = t * BK;
    const size_t qoff = (size_t)(kk >> 3) * N;
    b0 = qwb[qoff];
    b1 = qwb[qoff + 2 * (size_t)N];
    const int g = kk >> 7;
    zp = qzeros[(size_t)g * (N >> 3) + (gn >> 3)];
    sc = scales[(size_t)g * N + gn];
  };
  load_b(0, b0c, b1c, zpc, scc);

#pragma unroll 2
  for (int t = 0; t < NT; ++t) {
    {
      const char* g = xt_b + (size_t)(mt * NT + t) * TILE_BYTES +
                      (size_t)wid * 1024 + (size_t)lane * 16;
      char* l = ((char*)&As[0][0]) + wid * 1024;
      load_lds_16B(g, l);
      if (wid < 2) load_lds_16B(g + 8 * 1024, l + 8 * 1024);
    }
    {
      const unsigned z = (zpc >> ((gn & 7) * 4)) & 15u;
      const unsigned hz_u = 0x64006400u | z | (z << 16);
      const half2v hz2 = __builtin_bit_cast(half2v, hz_u);
      const half2v hs2 = __builtin_bit_cast(half2v, pkrtz_u32(scc, scc));
      const unsigned qvs[2] = {b0c, b1c};
#pragma unroll
      for (int q = 0; q < 2; ++q) {
        const int kr = b_kr0 + q * 2;
        const unsigned qv = qvs[q];
        uint4 wv;
        unsigned* wp = (unsigned*)&wv;
#pragma unroll
        for (int j = 0; j < 4; ++j) {
          const unsigned byte = qv >> (8 * j);
          const unsigned pq = 0x64006400u | (byte & 0xFu) | ((byte & 0xF0u) << 12);
          const half2v w2 = (__builtin_bit_cast(half2v, pq) - hz2) * hs2;
          wp[j] = __builtin_bit_cast(unsigned, w2);
        }
        *(uint4*)(&Bs[b_n][kr * 8]) = wv;
      }
    }

    __syncthreads();

    unsigned b0n, b1n, zpn;
    float scn;
    const int tn = (t + 1 < NT) ? (t + 1) : t;
    load_b(tn, b0n, b1n, zpn, scn);

    v8h af[4], bfr[4];
#pragma unroll
    for (int i = 0; i < 4; ++i) {
      af[i] = *(const v8h*)(&As[wm + i * 16 + lr][lk]);
      bfr[i] = *(const v8h*)(&Bs[wn + i * 16 + lr][lk]);
    }
#pragma unroll
    for (int mi = 0; mi < 4; ++mi) {
#pragma unroll
      for (int ni = 0; ni < 4; ++ni) {
        acc[mi][ni] = __builtin_amdgcn_mfma_f32_16x16x32_f16(
            af[mi], bfr[ni], acc[mi][ni], 0, 0, 0);
      }
    }

    __syncthreads();

    b0c = b0n; b1c = b1n; zpc = zpn; scc = scn;
  }

#pragma unroll
  for (int mi = 0; mi < 4; ++mi) {
#pragma unroll
    for (int ni = 0; ni < 4; ++ni) {
#pragma unroll
      for (int r = 0; r < 4; ++r) {
        const int row = m0 + wm + mi * 16 + (lane >> 4) * 4 + r;
        const int col = n0 + wn + ni * 16 + lr;
        out[(size_t)row * N + col] = acc[mi][ni][r];
      }
    }
  }
}

// ---------------- fallback 2: round-3 fully fused (128x128) ----------------
__global__ __launch_bounds__(256, 2)
void qgemm_fused(const float* __restrict__ x,
                 const unsigned* __restrict__ qweight,
                 const unsigned* __restrict__ qzeros,
                 const float* __restrict__ scales,
                 float* __restrict__ out, int M, int N, int K) {
  __shared__ short As[128][LDK];
  __shared__ short Bs[128][LDK];

  const int tid = threadIdx.x;
  const int lane = tid & 63;
  const int wid = tid >> 6;
  const int n0 = blockIdx.x * 128;
  const int m0 = blockIdx.y * 128;
  const int wm = (wid >> 1) * 64;
  const int wn = (wid & 1) * 64;
  const int lr = lane & 15;
  const int lk = (lane >> 4) * 8;

  const int a_row = tid >> 3;
  const int a_col = (tid & 7) * 4;
  const int b_n = tid & 127;
  const int b_kr0 = tid >> 7;
  const int gn = n0 + b_n;

  const float* xb = x + (size_t)(m0 + a_row) * K + a_col;
  const unsigned* qwb = qweight + (size_t)b_kr0 * N + gn;

  v4f acc[4][4] = {};
  const int NT = K / BK;

  float4 axc[4];
  unsigned b0c, b1c, zpc;
  float scc;

  auto load_step = [&](int t, float4 ax[4], unsigned& b0, unsigned& b1,
                       unsigned& zp, float& sc) {
    const int kk = t * BK;
#pragma unroll
    for (int p = 0; p < 4; ++p)
      ax[p] = *(const float4*)(xb + (size_t)(p * 32) * K + kk);
    const size_t qoff = (size_t)(kk >> 3) * N;
    b0 = qwb[qoff];
    b1 = qwb[qoff + 2 * (size_t)N];
    const int g = kk >> 7;
    zp = qzeros[(size_t)g * (N >> 3) + (gn >> 3)];
    sc = scales[(size_t)g * N + gn];
  };

  load_step(0, axc, b0c, b1c, zpc, scc);

#pragma unroll 2
  for (int t = 0; t < NT; ++t) {
    const unsigned z = (zpc >> ((gn & 7) * 4)) & 15u;
    const unsigned hz_u = 0x64006400u | z | (z << 16);
    const half2v hz2 = __builtin_bit_cast(half2v, hz_u);
    const half2v hs2 = __builtin_bit_cast(half2v, pkrtz_u32(scc, scc));

#pragma unroll
    for (int p = 0; p < 4; ++p) {
      const int row = p * 32 + a_row;
      uint2 pv;
      pv.x = pkrtz_u32(axc[p].x, axc[p].y);
      pv.y = pkrtz_u32(axc[p].z, axc[p].w);
      *(uint2*)(&As[row][a_col]) = pv;
    }
    {
      const unsigned qvs[2] = {b0c, b1c};
#pragma unroll
      for (int q = 0; q < 2; ++q) {
        const int kr = b_kr0 + q * 2;
        const unsigned qv = qvs[q];
        uint4 wv;
        unsigned* wp = (unsigned*)&wv;
#pragma unroll
        for (int j = 0; j < 4; ++j) {
          const unsigned byte = qv >> (8 * j);
          const unsigned pq = 0x64006400u | (byte & 0xFu) | ((byte & 0xF0u) << 12);
          const half2v w2 = (__builtin_bit_cast(half2v, pq) - hz2) * hs2;
          wp[j] = __builtin_bit_cast(unsigned, w2);
        }
        *(uint4*)(&Bs[b_n][kr * 8]) = wv;
      }
    }

    __syncthreads();

    float4 axn[4];
    unsigned b0n, b1n, zpn;
    float scn;
    const int tn = (t + 1 < NT) ? (t + 1) : t;
    load_step(tn, axn, b0n, b1n, zpn, scn);

    v8h af[4], bfr[4];
#pragma unroll
    for (int i = 0; i < 4; ++i) {
      af[i] = *(const v8h*)(&As[wm + i * 16 + lr][lk]);
      bfr[i] = *(const v8h*)(&Bs[wn + i * 16 + lr][lk]);
    }
#pragma unroll
    for (int mi = 0; mi < 4; ++mi) {
#pragma unroll
      for (int ni = 0; ni < 4; ++ni) {
        acc[mi][ni] = __builtin_amdgcn_mfma_f32_16x16x32_f16(
            af[mi], bfr[ni], acc[mi][ni], 0, 0, 0);
      }
    }

    __syncthreads();

#pragma unroll
    for (int p = 0; p < 4; ++p) axc[p] = axn[p];
    b0c = b0n; b1c = b1n; zpc = zpn; scc = scn;
  }

#pragma unroll
  for (int mi = 0; mi < 4; ++mi) {
#pragma unroll
    for (int ni = 0; ni < 4; ++ni) {
#pragma unroll
      for (int r = 0; r < 4; ++r) {
        const int row = m0 + wm + mi * 16 + (lane >> 4) * 4 + r;
        const int col = n0 + wn + ni * 16 + lr;
        out[(size_t)row * N + col] = acc[mi][ni][r];
      }
    }
  }
}

extern "C" void kernel_launch(void* const* d_in, const int* in_sizes, int n_in,
                              void* d_out, int out_size, void* d_ws, size_t ws_size,
                              hipStream_t stream) {
  const float* x = (const float*)d_in[0];
  const unsigned* qweight = (const unsigned*)d_in[1];
  const unsigned* qzeros = (const unsigned*)d_in[2];
  const float* scales = (const float*)d_in[3];
  float* out = (float*)d_out;

  const int K = 4096;
  const int N = 11008;
  const int M = in_sizes[0] / K;  // 4096

  const size_t A8 = (size_t)(M / 256) * (K / 64) * 32768;  // 33.6 MB
  const size_t B8 = (size_t)(N / 256) * (K / 64) * 32768;  // 90.2 MB
  const size_t A_BYTES = (size_t)(M / 128) * (K / 32) * TILE_BYTES;  // legacy

  if ((M % 256 == 0) && ws_size >= A8 + B8) {
    unsigned short* fa = (unsigned short*)d_ws;
    unsigned short* fb = (unsigned short*)((char*)d_ws + A8);
    const int nblk = (M / 256) * (K / 64) + (N / 256) * (K / 64);
    prep_ab<<<dim3(nblk), 512, 0, stream>>>(x, qweight, qzeros, scales, fa, fb, M, N, K);
    qgemm8<<<dim3((M / 256) * (N / 256)), 512, 0, stream>>>(fa, fb, out, M, N, K);
  } else if (ws_size >= A_BYTES) {
    unsigned short* xt = (unsigned short*)d_ws;
    prep_x<<<dim3(K / 32, M / 128), 320, 0, stream>>>(x, xt, K);
    qgemm_dma<<<dim3(N / 256, M / 128), 512, 0, stream>>>(xt, qweight, qzeros, scales,
                                                          out, M, N, K);
  } else {
    qgemm_fused<<<dim3(N / 128, M / 128), 256, 0, stream>>>(x, qweight, qzeros, scales,
                                                            out, M, N, K);
  }
}